// Round 1
// baseline (64.897 us; speedup 1.0000x reference)
//
#include <hip/hip_runtime.h>
#include <math.h>

#define N_PYR 30000
#define N_PV  3000
#define N_SST 2250
#define N_VIP 1500
#define N_NGC 750

// Constants from the reference
#define DT    0.5f
#define E_E   3.0f
#define E_I   (-0.5f)
// exp(-DT/TAU_NIC) = exp(-0.01), exp(-DT/TAU_MUS) = exp(-0.0025)
#define NIC_DECAY 0.9900498337491681f
#define MUS_DECAY 0.9975031223974601f

// ---------------------------------------------------------------------------
// Kernel 1: fused matvecs.
//   rows [0, 1500)        : vip_lr[r]  = w_lr_vip[r,:] . lre        (K=30000)
//   rows [1500, 2250)     : ngc_lr[r]  = w_lr_ngc[r,:] . lre        (K=30000)
//   rows [2250, 5250)     : pv_gap[r]  = w_pv_gap[r,:] . prev
//                                        - prev[r]*rowsum(w_pv_gap) (K=3000)
// Results go to ws: [0,1500)=vip_lr, [1500,2250)=ngc_lr, [2250,5250)=pv_gap
// ---------------------------------------------------------------------------
__global__ __launch_bounds__(256) void matvec_k(
    const float* __restrict__ w_vip, const float* __restrict__ w_ngc,
    const float* __restrict__ w_gap, const float* __restrict__ lre,
    const float* __restrict__ prev, float* __restrict__ ws)
{
    const int row = blockIdx.x;
    const int t   = threadIdx.x;

    const float4* __restrict__ wv;
    const float4* __restrict__ xv;
    int n4;
    bool is_gap = false;
    int gap_r = 0;
    int dst;

    if (row < N_VIP) {
        wv = (const float4*)(w_vip + (size_t)row * N_PYR);
        xv = (const float4*)lre;
        n4 = N_PYR / 4;
        dst = row;
    } else if (row < N_VIP + N_NGC) {
        const int r = row - N_VIP;
        wv = (const float4*)(w_ngc + (size_t)r * N_PYR);
        xv = (const float4*)lre;
        n4 = N_PYR / 4;
        dst = N_VIP + r;
    } else {
        gap_r = row - N_VIP - N_NGC;
        wv = (const float4*)(w_gap + (size_t)gap_r * N_PV);
        xv = (const float4*)prev;
        n4 = N_PV / 4;
        is_gap = true;
        dst = N_VIP + N_NGC + gap_r;
    }

    float acc = 0.0f;   // sum w*x
    float accw = 0.0f;  // sum w (only needed for gap rows)
    for (int i = t; i < n4; i += 256) {
        const float4 w = wv[i];
        const float4 x = xv[i];
        acc += w.x * x.x + w.y * x.y + w.z * x.z + w.w * x.w;
        if (is_gap) accw += w.x + w.y + w.z + w.w;
    }

    // wave(64) reduction
    #pragma unroll
    for (int off = 32; off > 0; off >>= 1) {
        acc  += __shfl_down(acc, off, 64);
        accw += __shfl_down(accw, off, 64);
    }

    __shared__ float s1[4];
    __shared__ float s2[4];
    const int wid = t >> 6, lane = t & 63;
    if (lane == 0) { s1[wid] = acc; s2[wid] = accw; }
    __syncthreads();
    if (t == 0) {
        float a = s1[0] + s1[1] + s1[2] + s1[3];
        if (is_gap) {
            const float rs = s2[0] + s2[1] + s2[2] + s2[3];
            a = a - prev[gap_r] * rs;
        }
        ws[dst] = a;
    }
}

// ---------------------------------------------------------------------------
// Kernel 2: LIF update for all 7500 interneurons.
// Output layout (out_size = 15000 floats):
//   [0,3000)      pv_spk
//   [3000,5250)   sst_spk
//   [5250,6750)   vip_spk
//   [6750,7500)   ngc_spk
//   [7500,10500)  pv_mem
//   [10500,12750) sst_mem
//   [12750,14250) vip_mem
//   [14250,15000) ngc_mem
// ---------------------------------------------------------------------------
struct LifArgs {
    const float *pv_g_exc, *pv_g_inh, *sst_g_exc, *sst_g_inh;
    const float *vip_g_exc, *vip_g_inh, *ngc_g_exc, *ngc_g_inh;
    const float *ffe, *ach, *nic, *mus;
    const float *pv_gL, *pv_tau, *pv_vth, *pv_ainc, *pv_v, *pv_ad;
    const float *sst_gL, *sst_tau, *sst_vth, *sst_ainc, *sst_v, *sst_ad;
    const float *vip_gL, *vip_tau, *vip_vth, *vip_ainc, *vip_v, *vip_ad;
    const float *ngc_gL, *ngc_tau, *ngc_vth, *ngc_ainc, *ngc_v, *ngc_ad;
    const float *ws;
    float *out;
};

__device__ __forceinline__ void lif_step(
    float v, float adapt, float gE, float gI, float iex,
    float gL, float tau, float vth, float& spk, float& vout)
{
    const float C = gL * tau;
    const float I = gL * (0.0f - v) + gE * (E_E - v) + gI * (E_I - v) + iex;
    const float v_new = v + DT * I / C;
    spk = (v_new >= vth + adapt) ? 1.0f : 0.0f;
    vout = (spk > 0.0f) ? 0.0f : v_new;
}

__global__ __launch_bounds__(256) void lif_k(LifArgs a)
{
    const int i = blockIdx.x * 256 + threadIdx.x;
    const int total = N_PV + N_SST + N_VIP + N_NGC;  // 7500
    if (i >= total) return;

    float spk, vout;
    if (i < N_PV) {
        const int j = i;
        const float gE = a.pv_g_exc[j] + a.ffe[j];
        const float iex = a.ws[N_VIP + N_NGC + j];  // pv_gap
        lif_step(a.pv_v[j], a.pv_ad[j], gE, a.pv_g_inh[j], iex,
                 a.pv_gL[j], a.pv_tau[j], a.pv_vth[j], spk, vout);
        a.out[j] = spk;
        a.out[total + j] = vout;
    } else if (i < N_PV + N_SST) {
        const int j = i - N_PV;
        lif_step(a.sst_v[j], a.sst_ad[j], a.sst_g_exc[j], a.sst_g_inh[j], 0.0f,
                 a.sst_gL[j], a.sst_tau[j], a.sst_vth[j], spk, vout);
        a.out[N_PV + j] = spk;
        a.out[total + N_PV + j] = vout;
    } else if (i < N_PV + N_SST + N_VIP) {
        const int j = i - N_PV - N_SST;
        const float nic = a.nic[j] * NIC_DECAY + a.ach[0];
        const float gE = a.vip_g_exc[j] + a.ws[j] + nic * 0.25f;
        lif_step(a.vip_v[j], a.vip_ad[j], gE, a.vip_g_inh[j], 0.0f,
                 a.vip_gL[j], a.vip_tau[j], a.vip_vth[j], spk, vout);
        a.out[N_PV + N_SST + j] = spk;
        a.out[total + N_PV + N_SST + j] = vout;
    } else {
        const int j = i - N_PV - N_SST - N_VIP;
        const float mus = a.mus[j] * MUS_DECAY + a.ach[0];
        const float gE = a.ngc_g_exc[j] + a.ws[N_VIP + j] + mus * 0.2f;
        lif_step(a.ngc_v[j], a.ngc_ad[j], gE, a.ngc_g_inh[j], 0.0f,
                 a.ngc_gL[j], a.ngc_tau[j], a.ngc_vth[j], spk, vout);
        a.out[N_PV + N_SST + N_VIP + j] = spk;
        a.out[total + N_PV + N_SST + N_VIP + j] = vout;
    }
}

extern "C" void kernel_launch(void* const* d_in, const int* in_sizes, int n_in,
                              void* d_out, int out_size, void* d_ws, size_t ws_size,
                              hipStream_t stream) {
    const float* pv_g_exc  = (const float*)d_in[0];
    const float* pv_g_inh  = (const float*)d_in[1];
    const float* sst_g_exc = (const float*)d_in[2];
    const float* sst_g_inh = (const float*)d_in[3];
    const float* vip_g_exc = (const float*)d_in[4];
    const float* vip_g_inh = (const float*)d_in[5];
    const float* ngc_g_exc = (const float*)d_in[6];
    const float* ngc_g_inh = (const float*)d_in[7];
    const float* ffe       = (const float*)d_in[8];
    const float* lre       = (const float*)d_in[9];
    const float* ach       = (const float*)d_in[10];
    const float* w_lr_vip  = (const float*)d_in[11];
    const float* w_lr_ngc  = (const float*)d_in[12];
    const float* w_pv_gap  = (const float*)d_in[13];
    const float* prev_pv   = (const float*)d_in[14];
    const float* nic_trace = (const float*)d_in[15];
    const float* mus_trace = (const float*)d_in[16];

    const float* pv_gL   = (const float*)d_in[17];
    const float* pv_tau  = (const float*)d_in[18];
    const float* pv_vth  = (const float*)d_in[19];
    const float* pv_ainc = (const float*)d_in[20];
    const float* pv_v    = (const float*)d_in[21];
    const float* pv_ad   = (const float*)d_in[22];

    const float* sst_gL   = (const float*)d_in[23];
    const float* sst_tau  = (const float*)d_in[24];
    const float* sst_vth  = (const float*)d_in[25];
    const float* sst_ainc = (const float*)d_in[26];
    const float* sst_v    = (const float*)d_in[27];
    const float* sst_ad   = (const float*)d_in[28];

    const float* vip_gL   = (const float*)d_in[29];
    const float* vip_tau  = (const float*)d_in[30];
    const float* vip_vth  = (const float*)d_in[31];
    const float* vip_ainc = (const float*)d_in[32];
    const float* vip_v    = (const float*)d_in[33];
    const float* vip_ad   = (const float*)d_in[34];

    const float* ngc_gL   = (const float*)d_in[35];
    const float* ngc_tau  = (const float*)d_in[36];
    const float* ngc_vth  = (const float*)d_in[37];
    const float* ngc_ainc = (const float*)d_in[38];
    const float* ngc_v    = (const float*)d_in[39];
    const float* ngc_ad   = (const float*)d_in[40];

    float* ws  = (float*)d_ws;
    float* out = (float*)d_out;

    // Kernel 1: 1500 + 750 + 3000 = 5250 rows, one block each.
    matvec_k<<<N_VIP + N_NGC + N_PV, 256, 0, stream>>>(
        w_lr_vip, w_lr_ngc, w_pv_gap, lre, prev_pv, ws);

    // Kernel 2: 7500 neurons.
    LifArgs a;
    a.pv_g_exc = pv_g_exc; a.pv_g_inh = pv_g_inh;
    a.sst_g_exc = sst_g_exc; a.sst_g_inh = sst_g_inh;
    a.vip_g_exc = vip_g_exc; a.vip_g_inh = vip_g_inh;
    a.ngc_g_exc = ngc_g_exc; a.ngc_g_inh = ngc_g_inh;
    a.ffe = ffe; a.ach = ach; a.nic = nic_trace; a.mus = mus_trace;
    a.pv_gL = pv_gL; a.pv_tau = pv_tau; a.pv_vth = pv_vth; a.pv_ainc = pv_ainc;
    a.pv_v = pv_v; a.pv_ad = pv_ad;
    a.sst_gL = sst_gL; a.sst_tau = sst_tau; a.sst_vth = sst_vth; a.sst_ainc = sst_ainc;
    a.sst_v = sst_v; a.sst_ad = sst_ad;
    a.vip_gL = vip_gL; a.vip_tau = vip_tau; a.vip_vth = vip_vth; a.vip_ainc = vip_ainc;
    a.vip_v = vip_v; a.vip_ad = vip_ad;
    a.ngc_gL = ngc_gL; a.ngc_tau = ngc_tau; a.ngc_vth = ngc_vth; a.ngc_ainc = ngc_ainc;
    a.ngc_v = ngc_v; a.ngc_ad = ngc_ad;
    a.ws = ws; a.out = out;

    lif_k<<<(N_PV + N_SST + N_VIP + N_NGC + 255) / 256, 256, 0, stream>>>(a);
}

// Round 2
// 56.505 us; speedup vs baseline: 1.1485x; 1.1485x over previous
//
#include <hip/hip_runtime.h>
#include <math.h>

#define N_PYR 30000
#define N_PV  3000
#define N_SST 2250
#define N_VIP 1500
#define N_NGC 750

#define DT    0.5f
#define E_E   3.0f
#define E_I   (-0.5f)
// exp(-DT/TAU_NIC) = exp(-0.01), exp(-DT/TAU_MUS) = exp(-0.0025)
#define NIC_DECAY 0.9900498337491681f
#define MUS_DECAY 0.9975031223974601f

// Blocks: [0,750) VIP pairs, [750,1125) NGC pairs, [1125,2625) PV-gap pairs.
#define B_VIP 750
#define B_NGC 375
#define B_PV  1500

__device__ __forceinline__ float dot4(const float4 w, const float4 x) {
    return w.x * x.x + w.y * x.y + w.z * x.z + w.w * x.w;
}
__device__ __forceinline__ float sum4(const float4 w) {
    return w.x + w.y + w.z + w.w;
}

// ---------------------------------------------------------------------------
// Kernel 1: fused matvecs, 2 rows per block, unroll x2.
//   ws[0,1500)    = w_lr_vip . lre
//   ws[1500,2250) = w_lr_ngc . lre
//   ws[2250,5250) = w_pv_gap . prev - prev*rowsum(w_pv_gap)
// ---------------------------------------------------------------------------
__global__ __launch_bounds__(256) void matvec_k(
    const float* __restrict__ w_vip, const float* __restrict__ w_ngc,
    const float* __restrict__ w_gap, const float* __restrict__ lre,
    const float* __restrict__ prev, float* __restrict__ ws)
{
    const int b = blockIdx.x;
    const int t = threadIdx.x;

    const float4* __restrict__ w0;
    const float4* __restrict__ w1;
    const float4* __restrict__ xv;
    int n4;
    bool is_gap = false;
    int r0 = 0;   // first row index within its own population (for prev[])
    int dst;

    if (b < B_VIP) {
        r0 = 2 * b;
        w0 = (const float4*)(w_vip + (size_t)r0 * N_PYR);
        w1 = (const float4*)(w_vip + (size_t)(r0 + 1) * N_PYR);
        xv = (const float4*)lre;
        n4 = N_PYR / 4;
        dst = r0;
    } else if (b < B_VIP + B_NGC) {
        r0 = 2 * (b - B_VIP);
        w0 = (const float4*)(w_ngc + (size_t)r0 * N_PYR);
        w1 = (const float4*)(w_ngc + (size_t)(r0 + 1) * N_PYR);
        xv = (const float4*)lre;
        n4 = N_PYR / 4;
        dst = N_VIP + r0;
    } else {
        r0 = 2 * (b - B_VIP - B_NGC);
        w0 = (const float4*)(w_gap + (size_t)r0 * N_PV);
        w1 = (const float4*)(w_gap + (size_t)(r0 + 1) * N_PV);
        xv = (const float4*)prev;
        n4 = N_PV / 4;
        is_gap = true;
        dst = N_VIP + N_NGC + r0;
    }

    float a0 = 0.0f, a1 = 0.0f;   // dot products
    float s0 = 0.0f, s1 = 0.0f;   // row sums (gap only)

    int i = t;
    for (; i + 256 < n4; i += 512) {
        const float4 xA  = xv[i];
        const float4 xB  = xv[i + 256];
        const float4 wA0 = w0[i];
        const float4 wB0 = w0[i + 256];
        const float4 wA1 = w1[i];
        const float4 wB1 = w1[i + 256];
        a0 += dot4(wA0, xA) + dot4(wB0, xB);
        a1 += dot4(wA1, xA) + dot4(wB1, xB);
        if (is_gap) {
            s0 += sum4(wA0) + sum4(wB0);
            s1 += sum4(wA1) + sum4(wB1);
        }
    }
    if (i < n4) {
        const float4 xA  = xv[i];
        const float4 wA0 = w0[i];
        const float4 wA1 = w1[i];
        a0 += dot4(wA0, xA);
        a1 += dot4(wA1, xA);
        if (is_gap) {
            s0 += sum4(wA0);
            s1 += sum4(wA1);
        }
    }

    // wave(64) butterfly reduction on all four accumulators
    #pragma unroll
    for (int off = 32; off > 0; off >>= 1) {
        a0 += __shfl_down(a0, off, 64);
        a1 += __shfl_down(a1, off, 64);
        s0 += __shfl_down(s0, off, 64);
        s1 += __shfl_down(s1, off, 64);
    }

    __shared__ float sm[4][4];
    const int wid = t >> 6, lane = t & 63;
    if (lane == 0) {
        sm[wid][0] = a0; sm[wid][1] = a1; sm[wid][2] = s0; sm[wid][3] = s1;
    }
    __syncthreads();
    if (t < 2) {
        float a = sm[0][t] + sm[1][t] + sm[2][t] + sm[3][t];
        if (is_gap) {
            const float rs = sm[0][2 + t] + sm[1][2 + t] + sm[2][2 + t] + sm[3][2 + t];
            a -= prev[r0 + t] * rs;
        }
        ws[dst + t] = a;
    }
}

// ---------------------------------------------------------------------------
// Kernel 2: LIF update for all 7500 interneurons.
// Output layout (out_size = 15000 floats):
//   [0,3000) pv_spk | [3000,5250) sst_spk | [5250,6750) vip_spk |
//   [6750,7500) ngc_spk | then the 4 mem arrays in the same order.
// ---------------------------------------------------------------------------
struct LifArgs {
    const float *pv_g_exc, *pv_g_inh, *sst_g_exc, *sst_g_inh;
    const float *vip_g_exc, *vip_g_inh, *ngc_g_exc, *ngc_g_inh;
    const float *ffe, *ach, *nic, *mus;
    const float *pv_gL, *pv_tau, *pv_vth, *pv_v, *pv_ad;
    const float *sst_gL, *sst_tau, *sst_vth, *sst_v, *sst_ad;
    const float *vip_gL, *vip_tau, *vip_vth, *vip_v, *vip_ad;
    const float *ngc_gL, *ngc_tau, *ngc_vth, *ngc_v, *ngc_ad;
    const float *ws;
    float *out;
};

__device__ __forceinline__ void lif_step(
    float v, float adapt, float gE, float gI, float iex,
    float gL, float tau, float vth, float& spk, float& vout)
{
    const float C = gL * tau;
    const float I = gL * (0.0f - v) + gE * (E_E - v) + gI * (E_I - v) + iex;
    const float v_new = v + DT * I / C;
    spk = (v_new >= vth + adapt) ? 1.0f : 0.0f;
    vout = (spk > 0.0f) ? 0.0f : v_new;
}

__global__ __launch_bounds__(256) void lif_k(LifArgs a)
{
    const int i = blockIdx.x * 256 + threadIdx.x;
    const int total = N_PV + N_SST + N_VIP + N_NGC;  // 7500
    if (i >= total) return;

    float spk, vout;
    if (i < N_PV) {
        const int j = i;
        const float gE = a.pv_g_exc[j] + a.ffe[j];
        const float iex = a.ws[N_VIP + N_NGC + j];
        lif_step(a.pv_v[j], a.pv_ad[j], gE, a.pv_g_inh[j], iex,
                 a.pv_gL[j], a.pv_tau[j], a.pv_vth[j], spk, vout);
        a.out[j] = spk;
        a.out[total + j] = vout;
    } else if (i < N_PV + N_SST) {
        const int j = i - N_PV;
        lif_step(a.sst_v[j], a.sst_ad[j], a.sst_g_exc[j], a.sst_g_inh[j], 0.0f,
                 a.sst_gL[j], a.sst_tau[j], a.sst_vth[j], spk, vout);
        a.out[N_PV + j] = spk;
        a.out[total + N_PV + j] = vout;
    } else if (i < N_PV + N_SST + N_VIP) {
        const int j = i - N_PV - N_SST;
        const float nic = a.nic[j] * NIC_DECAY + a.ach[0];
        const float gE = a.vip_g_exc[j] + a.ws[j] + nic * 0.25f;
        lif_step(a.vip_v[j], a.vip_ad[j], gE, a.vip_g_inh[j], 0.0f,
                 a.vip_gL[j], a.vip_tau[j], a.vip_vth[j], spk, vout);
        a.out[N_PV + N_SST + j] = spk;
        a.out[total + N_PV + N_SST + j] = vout;
    } else {
        const int j = i - N_PV - N_SST - N_VIP;
        const float mus = a.mus[j] * MUS_DECAY + a.ach[0];
        const float gE = a.ngc_g_exc[j] + a.ws[N_VIP + j] + mus * 0.2f;
        lif_step(a.ngc_v[j], a.ngc_ad[j], gE, a.ngc_g_inh[j], 0.0f,
                 a.ngc_gL[j], a.ngc_tau[j], a.ngc_vth[j], spk, vout);
        a.out[N_PV + N_SST + N_VIP + j] = spk;
        a.out[total + N_PV + N_SST + N_VIP + j] = vout;
    }
}

extern "C" void kernel_launch(void* const* d_in, const int* in_sizes, int n_in,
                              void* d_out, int out_size, void* d_ws, size_t ws_size,
                              hipStream_t stream) {
    const float* pv_g_exc  = (const float*)d_in[0];
    const float* pv_g_inh  = (const float*)d_in[1];
    const float* sst_g_exc = (const float*)d_in[2];
    const float* sst_g_inh = (const float*)d_in[3];
    const float* vip_g_exc = (const float*)d_in[4];
    const float* vip_g_inh = (const float*)d_in[5];
    const float* ngc_g_exc = (const float*)d_in[6];
    const float* ngc_g_inh = (const float*)d_in[7];
    const float* ffe       = (const float*)d_in[8];
    const float* lre       = (const float*)d_in[9];
    const float* ach       = (const float*)d_in[10];
    const float* w_lr_vip  = (const float*)d_in[11];
    const float* w_lr_ngc  = (const float*)d_in[12];
    const float* w_pv_gap  = (const float*)d_in[13];
    const float* prev_pv   = (const float*)d_in[14];
    const float* nic_trace = (const float*)d_in[15];
    const float* mus_trace = (const float*)d_in[16];

    const float* pv_gL   = (const float*)d_in[17];
    const float* pv_tau  = (const float*)d_in[18];
    const float* pv_vth  = (const float*)d_in[19];
    const float* pv_v    = (const float*)d_in[21];
    const float* pv_ad   = (const float*)d_in[22];

    const float* sst_gL   = (const float*)d_in[23];
    const float* sst_tau  = (const float*)d_in[24];
    const float* sst_vth  = (const float*)d_in[25];
    const float* sst_v    = (const float*)d_in[27];
    const float* sst_ad   = (const float*)d_in[28];

    const float* vip_gL   = (const float*)d_in[29];
    const float* vip_tau  = (const float*)d_in[30];
    const float* vip_vth  = (const float*)d_in[31];
    const float* vip_v    = (const float*)d_in[33];
    const float* vip_ad   = (const float*)d_in[34];

    const float* ngc_gL   = (const float*)d_in[35];
    const float* ngc_tau  = (const float*)d_in[36];
    const float* ngc_vth  = (const float*)d_in[37];
    const float* ngc_v    = (const float*)d_in[39];
    const float* ngc_ad   = (const float*)d_in[40];

    float* ws  = (float*)d_ws;
    float* out = (float*)d_out;

    matvec_k<<<B_VIP + B_NGC + B_PV, 256, 0, stream>>>(
        w_lr_vip, w_lr_ngc, w_pv_gap, lre, prev_pv, ws);

    LifArgs a;
    a.pv_g_exc = pv_g_exc; a.pv_g_inh = pv_g_inh;
    a.sst_g_exc = sst_g_exc; a.sst_g_inh = sst_g_inh;
    a.vip_g_exc = vip_g_exc; a.vip_g_inh = vip_g_inh;
    a.ngc_g_exc = ngc_g_exc; a.ngc_g_inh = ngc_g_inh;
    a.ffe = ffe; a.ach = ach; a.nic = nic_trace; a.mus = mus_trace;
    a.pv_gL = pv_gL; a.pv_tau = pv_tau; a.pv_vth = pv_vth;
    a.pv_v = pv_v; a.pv_ad = pv_ad;
    a.sst_gL = sst_gL; a.sst_tau = sst_tau; a.sst_vth = sst_vth;
    a.sst_v = sst_v; a.sst_ad = sst_ad;
    a.vip_gL = vip_gL; a.vip_tau = vip_tau; a.vip_vth = vip_vth;
    a.vip_v = vip_v; a.vip_ad = vip_ad;
    a.ngc_gL = ngc_gL; a.ngc_tau = ngc_tau; a.ngc_vth = ngc_vth;
    a.ngc_v = ngc_v; a.ngc_ad = ngc_ad;
    a.ws = ws; a.out = out;

    lif_k<<<(N_PV + N_SST + N_VIP + N_NGC + 255) / 256, 256, 0, stream>>>(a);
}

// Round 3
// 53.156 us; speedup vs baseline: 1.2209x; 1.0630x over previous
//
#include <hip/hip_runtime.h>
#include <math.h>

#define N_PYR 30000
#define N_PV  3000
#define N_SST 2250
#define N_VIP 1500
#define N_NGC 750
#define N_BIG (N_VIP + N_NGC)   // 2250 "big" rows (K = 30000)

#define DT    0.5f
#define E_E   3.0f
#define E_I   (-0.5f)
#define NIC_DECAY 0.9900498337491681f   // exp(-0.5/50)
#define MUS_DECAY 0.9975031223974601f   // exp(-0.5/200)

// Big rows: 2 rows/block x 2 K-chunks -> 2250 blocks of 120 KB weight reads.
// Gap rows: 2 rows/block, full K     -> 1500 blocks of 24 KB.
#define BIG_PAIRS   (N_BIG / 2)          // 1125
#define BIG_BLOCKS  (BIG_PAIRS * 2)      // 2250
#define GAP_BLOCKS  (N_PV / 2)           // 1500
#define KCHUNK      (N_PYR / 2)          // 15000 floats per chunk

// ws layout:
//   [0, 2250)        big-row partials, K-chunk 0 (VIP rows then NGC rows)
//   [2250, 4500)     big-row partials, K-chunk 1
//   [4500, 7500)     pv_gap results
#define WS_PART1 N_BIG
#define WS_GAP   (2 * N_BIG)

__device__ __forceinline__ float dot4(const float4 w, const float4 x) {
    return w.x * x.x + w.y * x.y + w.z * x.z + w.w * x.w;
}
__device__ __forceinline__ float sum4(const float4 w) {
    return w.x + w.y + w.z + w.w;
}

__global__ __launch_bounds__(256) void matvec_k(
    const float* __restrict__ w_vip, const float* __restrict__ w_ngc,
    const float* __restrict__ w_gap, const float* __restrict__ lre,
    const float* __restrict__ prev, float* __restrict__ ws)
{
    const int b = blockIdx.x;
    const int t = threadIdx.x;

    const float4* __restrict__ w0;
    const float4* __restrict__ w1;
    const float4* __restrict__ xv;
    int n4;
    bool is_gap = false;
    int r0 = 0;      // row index within population (for prev[] on gap rows)
    int dst;

    if (b < BIG_BLOCKS) {
        const int pair  = b >> 1;
        const int chunk = b & 1;
        r0 = 2 * pair;                      // big-row index, 0..2249
        const float* wbase = (r0 < N_VIP)
            ? (w_vip + (size_t)r0 * N_PYR)
            : (w_ngc + (size_t)(r0 - N_VIP) * N_PYR);
        w0 = (const float4*)(wbase + chunk * KCHUNK);
        w1 = (const float4*)(wbase + N_PYR + chunk * KCHUNK);
        xv = (const float4*)(lre + chunk * KCHUNK);
        n4 = KCHUNK / 4;                    // 3750
        dst = chunk * N_BIG + r0;
    } else {
        const int g = b - BIG_BLOCKS;
        r0 = 2 * g;
        w0 = (const float4*)(w_gap + (size_t)r0 * N_PV);
        w1 = (const float4*)(w_gap + (size_t)(r0 + 1) * N_PV);
        xv = (const float4*)prev;
        n4 = N_PV / 4;                      // 750
        is_gap = true;
        dst = WS_GAP + r0;
    }

    float a0 = 0.0f, a1 = 0.0f;
    float s0 = 0.0f, s1 = 0.0f;

    int i = t;
    // unroll x4: 12 independent loads in flight per iteration
    for (; i + 768 < n4; i += 1024) {
        const float4 xA = xv[i];
        const float4 xB = xv[i + 256];
        const float4 xC = xv[i + 512];
        const float4 xD = xv[i + 768];
        const float4 wA0 = w0[i];
        const float4 wB0 = w0[i + 256];
        const float4 wC0 = w0[i + 512];
        const float4 wD0 = w0[i + 768];
        const float4 wA1 = w1[i];
        const float4 wB1 = w1[i + 256];
        const float4 wC1 = w1[i + 512];
        const float4 wD1 = w1[i + 768];
        a0 += dot4(wA0, xA) + dot4(wB0, xB) + dot4(wC0, xC) + dot4(wD0, xD);
        a1 += dot4(wA1, xA) + dot4(wB1, xB) + dot4(wC1, xC) + dot4(wD1, xD);
        if (is_gap) {
            s0 += sum4(wA0) + sum4(wB0) + sum4(wC0) + sum4(wD0);
            s1 += sum4(wA1) + sum4(wB1) + sum4(wC1) + sum4(wD1);
        }
    }
    // unroll x2 tail
    for (; i + 256 < n4; i += 512) {
        const float4 xA = xv[i];
        const float4 xB = xv[i + 256];
        const float4 wA0 = w0[i];
        const float4 wB0 = w0[i + 256];
        const float4 wA1 = w1[i];
        const float4 wB1 = w1[i + 256];
        a0 += dot4(wA0, xA) + dot4(wB0, xB);
        a1 += dot4(wA1, xA) + dot4(wB1, xB);
        if (is_gap) {
            s0 += sum4(wA0) + sum4(wB0);
            s1 += sum4(wA1) + sum4(wB1);
        }
    }
    if (i < n4) {
        const float4 xA = xv[i];
        const float4 wA0 = w0[i];
        const float4 wA1 = w1[i];
        a0 += dot4(wA0, xA);
        a1 += dot4(wA1, xA);
        if (is_gap) {
            s0 += sum4(wA0);
            s1 += sum4(wA1);
        }
    }

    #pragma unroll
    for (int off = 32; off > 0; off >>= 1) {
        a0 += __shfl_down(a0, off, 64);
        a1 += __shfl_down(a1, off, 64);
        s0 += __shfl_down(s0, off, 64);
        s1 += __shfl_down(s1, off, 64);
    }

    __shared__ float sm[4][4];
    const int wid = t >> 6, lane = t & 63;
    if (lane == 0) {
        sm[wid][0] = a0; sm[wid][1] = a1; sm[wid][2] = s0; sm[wid][3] = s1;
    }
    __syncthreads();
    if (t < 2) {
        float a = sm[0][t] + sm[1][t] + sm[2][t] + sm[3][t];
        if (is_gap) {
            const float rs = sm[0][2 + t] + sm[1][2 + t] + sm[2][2 + t] + sm[3][2 + t];
            a -= prev[r0 + t] * rs;
        }
        ws[dst + t] = a;
    }
}

// ---------------------------------------------------------------------------
// Kernel 2: LIF update for all 7500 interneurons.
// ---------------------------------------------------------------------------
struct LifArgs {
    const float *pv_g_exc, *pv_g_inh, *sst_g_exc, *sst_g_inh;
    const float *vip_g_exc, *vip_g_inh, *ngc_g_exc, *ngc_g_inh;
    const float *ffe, *ach, *nic, *mus;
    const float *pv_gL, *pv_tau, *pv_vth, *pv_v, *pv_ad;
    const float *sst_gL, *sst_tau, *sst_vth, *sst_v, *sst_ad;
    const float *vip_gL, *vip_tau, *vip_vth, *vip_v, *vip_ad;
    const float *ngc_gL, *ngc_tau, *ngc_vth, *ngc_v, *ngc_ad;
    const float *ws;
    float *out;
};

__device__ __forceinline__ void lif_step(
    float v, float adapt, float gE, float gI, float iex,
    float gL, float tau, float vth, float& spk, float& vout)
{
    const float C = gL * tau;
    const float I = gL * (0.0f - v) + gE * (E_E - v) + gI * (E_I - v) + iex;
    const float v_new = v + DT * I / C;
    spk = (v_new >= vth + adapt) ? 1.0f : 0.0f;
    vout = (spk > 0.0f) ? 0.0f : v_new;
}

__global__ __launch_bounds__(256) void lif_k(LifArgs a)
{
    const int i = blockIdx.x * 256 + threadIdx.x;
    const int total = N_PV + N_SST + N_VIP + N_NGC;  // 7500
    if (i >= total) return;

    float spk, vout;
    if (i < N_PV) {
        const int j = i;
        const float gE = a.pv_g_exc[j] + a.ffe[j];
        const float iex = a.ws[WS_GAP + j];
        lif_step(a.pv_v[j], a.pv_ad[j], gE, a.pv_g_inh[j], iex,
                 a.pv_gL[j], a.pv_tau[j], a.pv_vth[j], spk, vout);
        a.out[j] = spk;
        a.out[total + j] = vout;
    } else if (i < N_PV + N_SST) {
        const int j = i - N_PV;
        lif_step(a.sst_v[j], a.sst_ad[j], a.sst_g_exc[j], a.sst_g_inh[j], 0.0f,
                 a.sst_gL[j], a.sst_tau[j], a.sst_vth[j], spk, vout);
        a.out[N_PV + j] = spk;
        a.out[total + N_PV + j] = vout;
    } else if (i < N_PV + N_SST + N_VIP) {
        const int j = i - N_PV - N_SST;
        const float nic = a.nic[j] * NIC_DECAY + a.ach[0];
        const float lr = a.ws[j] + a.ws[WS_PART1 + j];
        const float gE = a.vip_g_exc[j] + lr + nic * 0.25f;
        lif_step(a.vip_v[j], a.vip_ad[j], gE, a.vip_g_inh[j], 0.0f,
                 a.vip_gL[j], a.vip_tau[j], a.vip_vth[j], spk, vout);
        a.out[N_PV + N_SST + j] = spk;
        a.out[total + N_PV + N_SST + j] = vout;
    } else {
        const int j = i - N_PV - N_SST - N_VIP;
        const float mus = a.mus[j] * MUS_DECAY + a.ach[0];
        const float lr = a.ws[N_VIP + j] + a.ws[WS_PART1 + N_VIP + j];
        const float gE = a.ngc_g_exc[j] + lr + mus * 0.2f;
        lif_step(a.ngc_v[j], a.ngc_ad[j], gE, a.ngc_g_inh[j], 0.0f,
                 a.ngc_gL[j], a.ngc_tau[j], a.ngc_vth[j], spk, vout);
        a.out[N_PV + N_SST + N_VIP + j] = spk;
        a.out[total + N_PV + N_SST + N_VIP + j] = vout;
    }
}

extern "C" void kernel_launch(void* const* d_in, const int* in_sizes, int n_in,
                              void* d_out, int out_size, void* d_ws, size_t ws_size,
                              hipStream_t stream) {
    const float* pv_g_exc  = (const float*)d_in[0];
    const float* pv_g_inh  = (const float*)d_in[1];
    const float* sst_g_exc = (const float*)d_in[2];
    const float* sst_g_inh = (const float*)d_in[3];
    const float* vip_g_exc = (const float*)d_in[4];
    const float* vip_g_inh = (const float*)d_in[5];
    const float* ngc_g_exc = (const float*)d_in[6];
    const float* ngc_g_inh = (const float*)d_in[7];
    const float* ffe       = (const float*)d_in[8];
    const float* lre       = (const float*)d_in[9];
    const float* ach       = (const float*)d_in[10];
    const float* w_lr_vip  = (const float*)d_in[11];
    const float* w_lr_ngc  = (const float*)d_in[12];
    const float* w_pv_gap  = (const float*)d_in[13];
    const float* prev_pv   = (const float*)d_in[14];
    const float* nic_trace = (const float*)d_in[15];
    const float* mus_trace = (const float*)d_in[16];

    const float* pv_gL   = (const float*)d_in[17];
    const float* pv_tau  = (const float*)d_in[18];
    const float* pv_vth  = (const float*)d_in[19];
    const float* pv_v    = (const float*)d_in[21];
    const float* pv_ad   = (const float*)d_in[22];

    const float* sst_gL   = (const float*)d_in[23];
    const float* sst_tau  = (const float*)d_in[24];
    const float* sst_vth  = (const float*)d_in[25];
    const float* sst_v    = (const float*)d_in[27];
    const float* sst_ad   = (const float*)d_in[28];

    const float* vip_gL   = (const float*)d_in[29];
    const float* vip_tau  = (const float*)d_in[30];
    const float* vip_vth  = (const float*)d_in[31];
    const float* vip_v    = (const float*)d_in[33];
    const float* vip_ad   = (const float*)d_in[34];

    const float* ngc_gL   = (const float*)d_in[35];
    const float* ngc_tau  = (const float*)d_in[36];
    const float* ngc_vth  = (const float*)d_in[37];
    const float* ngc_v    = (const float*)d_in[39];
    const float* ngc_ad   = (const float*)d_in[40];

    float* ws  = (float*)d_ws;
    float* out = (float*)d_out;

    matvec_k<<<BIG_BLOCKS + GAP_BLOCKS, 256, 0, stream>>>(
        w_lr_vip, w_lr_ngc, w_pv_gap, lre, prev_pv, ws);

    LifArgs a;
    a.pv_g_exc = pv_g_exc; a.pv_g_inh = pv_g_inh;
    a.sst_g_exc = sst_g_exc; a.sst_g_inh = sst_g_inh;
    a.vip_g_exc = vip_g_exc; a.vip_g_inh = vip_g_inh;
    a.ngc_g_exc = ngc_g_exc; a.ngc_g_inh = ngc_g_inh;
    a.ffe = ffe; a.ach = ach; a.nic = nic_trace; a.mus = mus_trace;
    a.pv_gL = pv_gL; a.pv_tau = pv_tau; a.pv_vth = pv_vth;
    a.pv_v = pv_v; a.pv_ad = pv_ad;
    a.sst_gL = sst_gL; a.sst_tau = sst_tau; a.sst_vth = sst_vth;
    a.sst_v = sst_v; a.sst_ad = sst_ad;
    a.vip_gL = vip_gL; a.vip_tau = vip_tau; a.vip_vth = vip_vth;
    a.vip_v = vip_v; a.vip_ad = vip_ad;
    a.ngc_gL = ngc_gL; a.ngc_tau = ngc_tau; a.ngc_vth = ngc_vth;
    a.ngc_v = ngc_v; a.ngc_ad = ngc_ad;
    a.ws = ws; a.out = out;

    lif_k<<<(N_PV + N_SST + N_VIP + N_NGC + 255) / 256, 256, 0, stream>>>(a);
}

// Round 4
// 52.230 us; speedup vs baseline: 1.2425x; 1.0177x over previous
//
#include <hip/hip_runtime.h>
#include <math.h>

#define N_PYR 30000
#define N_PV  3000
#define N_SST 2250
#define N_VIP 1500
#define N_NGC 750
#define N_BIG (N_VIP + N_NGC)   // 2250 big rows (K = 30000)

#define DT    0.5f
#define E_E   3.0f
#define E_I   (-0.5f)
#define NIC_DECAY 0.9900498337491681f   // exp(-0.5/50)
#define MUS_DECAY 0.9975031223974601f   // exp(-0.5/200)

// Big rows: 4 rows/block x 4 K-chunks of 7500 -> 2252 blocks, 120 KB weights each.
// Gap rows: 4 rows/block, full K              -> 750 blocks, 48 KB each.
#define BIG_QUADS   ((N_BIG + 3) / 4)        // 563 (last quad has 2 rows)
#define N_CHUNKS    4
#define KCHUNK      (N_PYR / N_CHUNKS)       // 7500 floats
#define BIG_BLOCKS  (BIG_QUADS * N_CHUNKS)   // 2252
#define GAP_BLOCKS  (N_PV / 4)               // 750

// ws layout: partials[chunk][big_row] then gap results
//   [chunk*2250 + r] for chunk=0..3, r=0..2249   (9000 floats)
//   [9000 + j]       pv_gap, j=0..2999           (3000 floats)
#define WS_GAP (N_CHUNKS * N_BIG)

__device__ __forceinline__ float dot4(const float4 w, const float4 x) {
    return w.x * x.x + w.y * x.y + w.z * x.z + w.w * x.w;
}
__device__ __forceinline__ float sum4(const float4 w) {
    return w.x + w.y + w.z + w.w;
}

__global__ __launch_bounds__(256) void matvec_k(
    const float* __restrict__ w_vip, const float* __restrict__ w_ngc,
    const float* __restrict__ w_gap, const float* __restrict__ lre,
    const float* __restrict__ prev, float* __restrict__ ws)
{
    const int b = blockIdx.x;
    const int t = threadIdx.x;

    const float4* __restrict__ w0;
    const float4* __restrict__ w1;
    const float4* __restrict__ w2;
    const float4* __restrict__ w3;
    const float4* __restrict__ xv;
    int n4, r0, dst, nv;
    bool is_gap = false;

    if (b < BIG_BLOCKS) {
        const int q     = b >> 2;
        const int chunk = b & 3;
        r0 = 4 * q;
        nv = (N_BIG - r0 < 4) ? (N_BIG - r0) : 4;
        // per-row base (clamped for the short last quad)
        const float* bp[4];
        #pragma unroll
        for (int k = 0; k < 4; ++k) {
            int rr = r0 + k; if (rr > N_BIG - 1) rr = N_BIG - 1;
            const float* base = (rr < N_VIP)
                ? (w_vip + (size_t)rr * N_PYR)
                : (w_ngc + (size_t)(rr - N_VIP) * N_PYR);
            bp[k] = base + chunk * KCHUNK;
        }
        w0 = (const float4*)bp[0]; w1 = (const float4*)bp[1];
        w2 = (const float4*)bp[2]; w3 = (const float4*)bp[3];
        xv = (const float4*)(lre + chunk * KCHUNK);
        n4 = KCHUNK / 4;                    // 1875
        dst = chunk * N_BIG + r0;
    } else {
        const int g = b - BIG_BLOCKS;
        r0 = 4 * g;
        nv = 4;
        w0 = (const float4*)(w_gap + (size_t)r0 * N_PV);
        w1 = (const float4*)(w_gap + (size_t)(r0 + 1) * N_PV);
        w2 = (const float4*)(w_gap + (size_t)(r0 + 2) * N_PV);
        w3 = (const float4*)(w_gap + (size_t)(r0 + 3) * N_PV);
        xv = (const float4*)prev;
        n4 = N_PV / 4;                      // 750
        is_gap = true;
        dst = WS_GAP + r0;
    }

    float a0 = 0.f, a1 = 0.f, a2 = 0.f, a3 = 0.f;
    float s0 = 0.f, s1 = 0.f, s2 = 0.f, s3 = 0.f;

    int i = t;
    // unroll x2: 2 x-loads + 8 w-loads in flight per iteration
    for (; i + 256 < n4; i += 512) {
        const float4 xA = xv[i];
        const float4 xB = xv[i + 256];
        const float4 wA0 = w0[i];       const float4 wA1 = w1[i];
        const float4 wA2 = w2[i];       const float4 wA3 = w3[i];
        const float4 wB0 = w0[i + 256]; const float4 wB1 = w1[i + 256];
        const float4 wB2 = w2[i + 256]; const float4 wB3 = w3[i + 256];
        a0 += dot4(wA0, xA) + dot4(wB0, xB);
        a1 += dot4(wA1, xA) + dot4(wB1, xB);
        a2 += dot4(wA2, xA) + dot4(wB2, xB);
        a3 += dot4(wA3, xA) + dot4(wB3, xB);
        if (is_gap) {
            s0 += sum4(wA0) + sum4(wB0);
            s1 += sum4(wA1) + sum4(wB1);
            s2 += sum4(wA2) + sum4(wB2);
            s3 += sum4(wA3) + sum4(wB3);
        }
    }
    if (i < n4) {
        const float4 xA = xv[i];
        const float4 wA0 = w0[i]; const float4 wA1 = w1[i];
        const float4 wA2 = w2[i]; const float4 wA3 = w3[i];
        a0 += dot4(wA0, xA);
        a1 += dot4(wA1, xA);
        a2 += dot4(wA2, xA);
        a3 += dot4(wA3, xA);
        if (is_gap) {
            s0 += sum4(wA0); s1 += sum4(wA1);
            s2 += sum4(wA2); s3 += sum4(wA3);
        }
    }

    #pragma unroll
    for (int off = 32; off > 0; off >>= 1) {
        a0 += __shfl_down(a0, off, 64);
        a1 += __shfl_down(a1, off, 64);
        a2 += __shfl_down(a2, off, 64);
        a3 += __shfl_down(a3, off, 64);
        s0 += __shfl_down(s0, off, 64);
        s1 += __shfl_down(s1, off, 64);
        s2 += __shfl_down(s2, off, 64);
        s3 += __shfl_down(s3, off, 64);
    }

    __shared__ float sm[4][8];
    const int wid = t >> 6, lane = t & 63;
    if (lane == 0) {
        sm[wid][0] = a0; sm[wid][1] = a1; sm[wid][2] = a2; sm[wid][3] = a3;
        sm[wid][4] = s0; sm[wid][5] = s1; sm[wid][6] = s2; sm[wid][7] = s3;
    }
    __syncthreads();
    if (t < nv) {
        float a = sm[0][t] + sm[1][t] + sm[2][t] + sm[3][t];
        if (is_gap) {
            const float rs = sm[0][4 + t] + sm[1][4 + t] + sm[2][4 + t] + sm[3][4 + t];
            a -= prev[r0 + t] * rs;
        }
        ws[dst + t] = a;
    }
}

// ---------------------------------------------------------------------------
// Kernel 2: LIF update for all 7500 interneurons.
// ---------------------------------------------------------------------------
struct LifArgs {
    const float *pv_g_exc, *pv_g_inh, *sst_g_exc, *sst_g_inh;
    const float *vip_g_exc, *vip_g_inh, *ngc_g_exc, *ngc_g_inh;
    const float *ffe, *ach, *nic, *mus;
    const float *pv_gL, *pv_tau, *pv_vth, *pv_v, *pv_ad;
    const float *sst_gL, *sst_tau, *sst_vth, *sst_v, *sst_ad;
    const float *vip_gL, *vip_tau, *vip_vth, *vip_v, *vip_ad;
    const float *ngc_gL, *ngc_tau, *ngc_vth, *ngc_v, *ngc_ad;
    const float *ws;
    float *out;
};

__device__ __forceinline__ void lif_step(
    float v, float adapt, float gE, float gI, float iex,
    float gL, float tau, float vth, float& spk, float& vout)
{
    const float C = gL * tau;
    const float I = gL * (0.0f - v) + gE * (E_E - v) + gI * (E_I - v) + iex;
    const float v_new = v + DT * I / C;
    spk = (v_new >= vth + adapt) ? 1.0f : 0.0f;
    vout = (spk > 0.0f) ? 0.0f : v_new;
}

__global__ __launch_bounds__(256) void lif_k(LifArgs a)
{
    const int i = blockIdx.x * 256 + threadIdx.x;
    const int total = N_PV + N_SST + N_VIP + N_NGC;  // 7500
    if (i >= total) return;

    float spk, vout;
    if (i < N_PV) {
        const int j = i;
        const float gE = a.pv_g_exc[j] + a.ffe[j];
        const float iex = a.ws[WS_GAP + j];
        lif_step(a.pv_v[j], a.pv_ad[j], gE, a.pv_g_inh[j], iex,
                 a.pv_gL[j], a.pv_tau[j], a.pv_vth[j], spk, vout);
        a.out[j] = spk;
        a.out[total + j] = vout;
    } else if (i < N_PV + N_SST) {
        const int j = i - N_PV;
        lif_step(a.sst_v[j], a.sst_ad[j], a.sst_g_exc[j], a.sst_g_inh[j], 0.0f,
                 a.sst_gL[j], a.sst_tau[j], a.sst_vth[j], spk, vout);
        a.out[N_PV + j] = spk;
        a.out[total + N_PV + j] = vout;
    } else if (i < N_PV + N_SST + N_VIP) {
        const int j = i - N_PV - N_SST;
        const float nic = a.nic[j] * NIC_DECAY + a.ach[0];
        const float lr = a.ws[j] + a.ws[N_BIG + j]
                       + a.ws[2 * N_BIG + j] + a.ws[3 * N_BIG + j];
        const float gE = a.vip_g_exc[j] + lr + nic * 0.25f;
        lif_step(a.vip_v[j], a.vip_ad[j], gE, a.vip_g_inh[j], 0.0f,
                 a.vip_gL[j], a.vip_tau[j], a.vip_vth[j], spk, vout);
        a.out[N_PV + N_SST + j] = spk;
        a.out[total + N_PV + N_SST + j] = vout;
    } else {
        const int j = i - N_PV - N_SST - N_VIP;
        const float mus = a.mus[j] * MUS_DECAY + a.ach[0];
        const int r = N_VIP + j;
        const float lr = a.ws[r] + a.ws[N_BIG + r]
                       + a.ws[2 * N_BIG + r] + a.ws[3 * N_BIG + r];
        const float gE = a.ngc_g_exc[j] + lr + mus * 0.2f;
        lif_step(a.ngc_v[j], a.ngc_ad[j], gE, a.ngc_g_inh[j], 0.0f,
                 a.ngc_gL[j], a.ngc_tau[j], a.ngc_vth[j], spk, vout);
        a.out[N_PV + N_SST + N_VIP + j] = spk;
        a.out[total + N_PV + N_SST + N_VIP + j] = vout;
    }
}

extern "C" void kernel_launch(void* const* d_in, const int* in_sizes, int n_in,
                              void* d_out, int out_size, void* d_ws, size_t ws_size,
                              hipStream_t stream) {
    const float* pv_g_exc  = (const float*)d_in[0];
    const float* pv_g_inh  = (const float*)d_in[1];
    const float* sst_g_exc = (const float*)d_in[2];
    const float* sst_g_inh = (const float*)d_in[3];
    const float* vip_g_exc = (const float*)d_in[4];
    const float* vip_g_inh = (const float*)d_in[5];
    const float* ngc_g_exc = (const float*)d_in[6];
    const float* ngc_g_inh = (const float*)d_in[7];
    const float* ffe       = (const float*)d_in[8];
    const float* lre       = (const float*)d_in[9];
    const float* ach       = (const float*)d_in[10];
    const float* w_lr_vip  = (const float*)d_in[11];
    const float* w_lr_ngc  = (const float*)d_in[12];
    const float* w_pv_gap  = (const float*)d_in[13];
    const float* prev_pv   = (const float*)d_in[14];
    const float* nic_trace = (const float*)d_in[15];
    const float* mus_trace = (const float*)d_in[16];

    const float* pv_gL   = (const float*)d_in[17];
    const float* pv_tau  = (const float*)d_in[18];
    const float* pv_vth  = (const float*)d_in[19];
    const float* pv_v    = (const float*)d_in[21];
    const float* pv_ad   = (const float*)d_in[22];

    const float* sst_gL   = (const float*)d_in[23];
    const float* sst_tau  = (const float*)d_in[24];
    const float* sst_vth  = (const float*)d_in[25];
    const float* sst_v    = (const float*)d_in[27];
    const float* sst_ad   = (const float*)d_in[28];

    const float* vip_gL   = (const float*)d_in[29];
    const float* vip_tau  = (const float*)d_in[30];
    const float* vip_vth  = (const float*)d_in[31];
    const float* vip_v    = (const float*)d_in[33];
    const float* vip_ad   = (const float*)d_in[34];

    const float* ngc_gL   = (const float*)d_in[35];
    const float* ngc_tau  = (const float*)d_in[36];
    const float* ngc_vth  = (const float*)d_in[37];
    const float* ngc_v    = (const float*)d_in[39];
    const float* ngc_ad   = (const float*)d_in[40];

    float* ws  = (float*)d_ws;
    float* out = (float*)d_out;

    matvec_k<<<BIG_BLOCKS + GAP_BLOCKS, 256, 0, stream>>>(
        w_lr_vip, w_lr_ngc, w_pv_gap, lre, prev_pv, ws);

    LifArgs a;
    a.pv_g_exc = pv_g_exc; a.pv_g_inh = pv_g_inh;
    a.sst_g_exc = sst_g_exc; a.sst_g_inh = sst_g_inh;
    a.vip_g_exc = vip_g_exc; a.vip_g_inh = vip_g_inh;
    a.ngc_g_exc = ngc_g_exc; a.ngc_g_inh = ngc_g_inh;
    a.ffe = ffe; a.ach = ach; a.nic = nic_trace; a.mus = mus_trace;
    a.pv_gL = pv_gL; a.pv_tau = pv_tau; a.pv_vth = pv_vth;
    a.pv_v = pv_v; a.pv_ad = pv_ad;
    a.sst_gL = sst_gL; a.sst_tau = sst_tau; a.sst_vth = sst_vth;
    a.sst_v = sst_v; a.sst_ad = sst_ad;
    a.vip_gL = vip_gL; a.vip_tau = vip_tau; a.vip_vth = vip_vth;
    a.vip_v = vip_v; a.vip_ad = vip_ad;
    a.ngc_gL = ngc_gL; a.ngc_tau = ngc_tau; a.ngc_vth = ngc_vth;
    a.ngc_v = ngc_v; a.ngc_ad = ngc_ad;
    a.ws = ws; a.out = out;

    lif_k<<<(N_PV + N_SST + N_VIP + N_NGC + 255) / 256, 256, 0, stream>>>(a);
}